// Round 10
// baseline (222.152 us; speedup 1.0000x reference)
//
#include <hip/hip_runtime.h>
#include <math.h>

namespace {
constexpr int Tn = 128, Bn = 16, An = 32, OBS = 256, Kh = 3, NACT = 9, HID = 32;
constexpr int TBA = Tn * Bn * An;   // 65536 rows through the MLP
constexpr int BA  = Bn * An;        // 512 LSTM sequences
constexpr int OUT_LP  = TBA * Kh;         // 196608: logprobs start
constexpr int OUT_ENT = TBA * Kh + TBA;   // 262144: entropies start

// fp16 weight pack offsets (elements)
constexpr int W1_OFF  = 0;       // 128x256
constexpr int W2_OFF  = 32768;   // 128x128
constexpr int W3_OFF  = 49152;   // 64x128
constexpr int WIH_OFF = 57344;   // 128x64
constexpr int W16_TOT = 65536;

typedef __fp16   pk16x2 __attribute__((ext_vector_type(2)));  // builtin-compatible
typedef _Float16 half8v __attribute__((ext_vector_type(8)));
typedef float    f32x4  __attribute__((ext_vector_type(4)));
}

__device__ __forceinline__ float fast_sig(float x) {
  return __builtin_amdgcn_rcpf(1.f + __expf(-x));
}
__device__ __forceinline__ float fast_tanh(float x) {   // 2*sig(2x)-1, saturates safely
  return fmaf(2.f, fast_sig(2.f * x), -1.f);
}
__device__ __forceinline__ unsigned h2bits(pk16x2 h) {
  return __builtin_bit_cast(unsigned, h);
}
__device__ __forceinline__ pk16x2 bits2h(unsigned u) {
  return __builtin_bit_cast(pk16x2, u);
}
__device__ __forceinline__ float dot2(pk16x2 a, pk16x2 b, float c) {
#if __has_builtin(__builtin_amdgcn_fdot2)
  return __builtin_amdgcn_fdot2(a, b, c, false);
#else
  c = fmaf((float)a.x, (float)b.x, c);
  return fmaf((float)a.y, (float)b.y, c);
#endif
}
// DPP cross-lane (VALU pipe, no DS): 0xB1=xor1, 0x4E=xor2, 0x124/0x128=row_ror 4/8
template<int CTRL>
__device__ __forceinline__ float dpp_movf(float x) {
  return __uint_as_float((unsigned)__builtin_amdgcn_mov_dpp(
      (int)__float_as_uint(x), CTRL, 0xF, 0xF, true));
}
__device__ __forceinline__ float dpp_swap1(float x) { return dpp_movf<0xB1>(x); }
// full reduction within each 16-lane row group, result in all 16 lanes
__device__ __forceinline__ float dpp_sum16(float v) {
  v += dpp_movf<0xB1>(v);  v += dpp_movf<0x4E>(v);
  v += dpp_movf<0x124>(v); v += dpp_movf<0x128>(v);
  return v;
}
__device__ __forceinline__ float dpp_max16(float v) {
  v = fmaxf(v, dpp_movf<0xB1>(v));  v = fmaxf(v, dpp_movf<0x4E>(v));
  v = fmaxf(v, dpp_movf<0x124>(v)); v = fmaxf(v, dpp_movf<0x128>(v));
  return v;
}

// ---------------------------------------------------------------------------
// Weight fp32->fp16 pre-conversion + actions echo (fused, one launch).
// Blocks [0,256): W16; blocks [256,1024): out[i] = (float)actions[i].
// ---------------------------------------------------------------------------
__global__ __launch_bounds__(256) void cvtw_act_kernel(
    const float* __restrict__ W1, const float* __restrict__ W2,
    const float* __restrict__ W3, const float* __restrict__ Wih,
    _Float16* __restrict__ w16, const int* __restrict__ actions,
    float* __restrict__ out)
{
  const int bid = blockIdx.x;
  if (bid < W16_TOT/256) {
    int i = bid * 256 + threadIdx.x;            // 0..65535
    float v;
    if (i < W2_OFF)       v = W1[i];
    else if (i < W3_OFF)  v = W2[i - W2_OFF];
    else if (i < WIH_OFF) v = W3[i - W3_OFF];
    else                  v = Wih[i - WIH_OFF];
    w16[i] = (_Float16)v;
  } else {
    int i = (bid - W16_TOT/256) * 256 + threadIdx.x;  // 0..196607
    out[i] = (float)actions[i];
  }
}

// ---------------------------------------------------------------------------
// Fused MLP trunk + LSTM input projection, f16 MFMA (fp32 accumulate):
//   z = tanh(tanh(x@W1'+b1)@W2'+b2)@W3'+b3 ; G1 = z@Wih' + bih + bhh
// G1 stored as uint2 per (row, unit): {pk(i,g), pk(f,o)}.
// ---------------------------------------------------------------------------
template<int ROWS, int WSTR>
__device__ __forceinline__ void stage_wh(const _Float16* __restrict__ Wg, int kofs,
                                         _Float16* __restrict__ wt, int tid)
{
#pragma unroll
  for (int it = 0; it < ROWS/32; ++it) {
    int idx = tid + it*256;
    int o = idx >> 3, g8 = idx & 7;
    *(half8v*)&wt[o*72 + g8*8] =
        *(const half8v*)&Wg[(size_t)o*WSTR + kofs + g8*8];
  }
}

template<int NOC, int XSTR>
__device__ __forceinline__ void mfma_slab(const _Float16* __restrict__ xsrc,
                                          const _Float16* __restrict__ wt,
                                          int rA, int ln, int quad, f32x4 acc[8])
{
#pragma unroll
  for (int kc = 0; kc < 2; ++kc) {
    half8v a = *(const half8v*)&xsrc[rA*XSTR + kc*32 + quad*8];
#pragma unroll
    for (int oc = 0; oc < NOC; ++oc) {
      half8v b = *(const half8v*)&wt[(oc*16 + ln)*72 + kc*32 + quad*8];
      acc[oc] = __builtin_amdgcn_mfma_f32_16x16x32_f16(a, b, acc[oc], 0, 0, 0);
    }
  }
}

__global__ __launch_bounds__(256) void mlp_kernel(
    const float* __restrict__ x, const _Float16* __restrict__ w16,
    const float* __restrict__ b1, const float* __restrict__ b2,
    const float* __restrict__ b3, const float* __restrict__ bih,
    const float* __restrict__ bhh, uint2* __restrict__ G1q)
{
  __shared__ __align__(16) _Float16 xs[64*72];    // x k-slab; reused for z
  __shared__ __align__(16) _Float16 wt[128*72];   // weight k-slab
  __shared__ __align__(16) _Float16 act[64*136];  // activations (reused in place)
  const _Float16* W1h  = w16 + W1_OFF;
  const _Float16* W2h  = w16 + W2_OFF;
  const _Float16* W3h  = w16 + W3_OFF;
  const _Float16* Wihh = w16 + WIH_OFF;
  const int tid  = threadIdx.x;
  const int w    = tid >> 6;
  const int lane = tid & 63;
  const int ln   = lane & 15;
  const int quad = lane >> 4;
  const int rA   = 16*w + ln;
  const int r0   = 16*w + quad*4;
  const int R0   = blockIdx.x * 64;
  f32x4 acc[8];

  // ---- layer 1: 256 -> 128, tanh (4 k-slabs of 64) ----
#pragma unroll
  for (int oc = 0; oc < 8; ++oc) acc[oc] = (f32x4)0.f;
  for (int kt = 0; kt < 4; ++kt) {
#pragma unroll
    for (int it = 0; it < 2; ++it) {           // stage x slab [64][64] -> fp16
      int idx = tid + it*256;
      int r = idx >> 3, g8 = idx & 7;
      const float* xp = &x[(size_t)(R0 + r)*OBS + kt*64 + g8*8];
      float4 v0 = *(const float4*)xp;
      float4 v1 = *(const float4*)(xp + 4);
      half8v hv = { (_Float16)v0.x, (_Float16)v0.y, (_Float16)v0.z, (_Float16)v0.w,
                    (_Float16)v1.x, (_Float16)v1.y, (_Float16)v1.z, (_Float16)v1.w };
      *(half8v*)&xs[r*72 + g8*8] = hv;
    }
    stage_wh<128, 256>(W1h, kt*64, wt, tid);
    __syncthreads();
    mfma_slab<8, 72>(xs, wt, rA, ln, quad, acc);
    __syncthreads();
  }
#pragma unroll
  for (int oc = 0; oc < 8; ++oc) {
    int o = oc*16 + ln;
    float bv = b1[o];
#pragma unroll
    for (int r = 0; r < 4; ++r)
      act[(r0 + r)*136 + o] = (_Float16)fast_tanh(acc[oc][r] + bv);
  }

  // ---- layer 2: 128 -> 128, tanh ----
#pragma unroll
  for (int oc = 0; oc < 8; ++oc) acc[oc] = (f32x4)0.f;
  for (int kt = 0; kt < 2; ++kt) {
    stage_wh<128, 128>(W2h, kt*64, wt, tid);
    __syncthreads();                            // publishes act writes + wt
    mfma_slab<8, 136>(act + kt*64, wt, rA, ln, quad, acc);
    __syncthreads();
  }
#pragma unroll
  for (int oc = 0; oc < 8; ++oc) {
    int o = oc*16 + ln;
    float bv = b2[o];
#pragma unroll
    for (int r = 0; r < 4; ++r)
      act[(r0 + r)*136 + o] = (_Float16)fast_tanh(acc[oc][r] + bv);
  }

  // ---- layer 3: 128 -> 64, linear -> z into xs buffer ----
#pragma unroll
  for (int oc = 0; oc < 4; ++oc) acc[oc] = (f32x4)0.f;
  for (int kt = 0; kt < 2; ++kt) {
    stage_wh<64, 128>(W3h, kt*64, wt, tid);
    __syncthreads();
    mfma_slab<4, 136>(act + kt*64, wt, rA, ln, quad, acc);
    __syncthreads();
  }
#pragma unroll
  for (int oc = 0; oc < 4; ++oc) {
    int o = oc*16 + ln;
    float bv = b3[o];
#pragma unroll
    for (int r = 0; r < 4; ++r)
      xs[(r0 + r)*72 + o] = (_Float16)(acc[oc][r] + bv);
  }

  // ---- layer 4: z(64) -> 128 gate inputs, all 4 gates of unit u packed ----
#pragma unroll
  for (int oc = 0; oc < 8; ++oc) acc[oc] = (f32x4)0.f;
  stage_wh<128, 64>(Wihh, 0, wt, tid);
  __syncthreads();                              // publishes z writes + wt
  mfma_slab<8, 72>(xs, wt, rA, ln, quad, acc);
#pragma unroll
  for (int p = 0; p < 2; ++p) {
    int ui = p*16 + ln;
    float bi = bih[ui]      + bhh[ui];
    float bf = bih[ui + 32] + bhh[ui + 32];
    float bg = bih[ui + 64] + bhh[ui + 64];
    float bo = bih[ui + 96] + bhh[ui + 96];
#pragma unroll
    for (int r = 0; r < 4; ++r) {
      int n = R0 + r0 + r;
      uint2 q;
      q.x = h2bits(__builtin_amdgcn_cvt_pkrtz(acc[p  ][r] + bi, acc[p+4][r] + bg));
      q.y = h2bits(__builtin_amdgcn_cvt_pkrtz(acc[p+2][r] + bf, acc[p+6][r] + bo));
      G1q[(size_t)n*32 + ui] = q;
    }
  }
}

// ---------------------------------------------------------------------------
// LSTM scan v8 + FUSED HEADS: 1 row per 64-lane wave, 512 blocks.
// Recurrence identical to v7 (SGPR done-masks, DPP h-swap, 4-phase G1
// pipeline). Head for step t-1 computed during phase t using the hp[]
// broadcast that the gate dot needs anyway: 48 lanes compute the 27 logits
// (lane = head hk=lane>>4, slot hj=lane&15, valid hj<9), softmax/entropy/
// chosen-logprob reduced within 16-lane groups via DPP-only reductions
// (no DS pipe). Y16 intermediate eliminated; entropies/logprob stored
// directly. Tail head pass for t=127 after the loop.
// ---------------------------------------------------------------------------
__global__ __launch_bounds__(64) void lstm_head_kernel(
    const uint2* __restrict__ G1q, const float* __restrict__ Whh,
    const int* __restrict__ done, const float* __restrict__ h0,
    const float* __restrict__ c0, const int* __restrict__ actions,
    const float* __restrict__ Wh, const float* __restrict__ bh,
    float* __restrict__ out)
{
  const int lane = threadIdx.x;        // 0..63
  const int u = lane & 31;
  const int row = blockIdx.x;          // 0..511
  const int b = row >> 5;

  pk16x2 wi[16], wf[16], wg[16], wo[16];   // Whh rows u, u+32, u+64, u+96
#pragma unroll
  for (int k4 = 0; k4 < 8; ++k4) {
    float4 a  = *(const float4*)&Whh[(u      )*HID + k4*4];
    float4 bq = *(const float4*)&Whh[(u + 32 )*HID + k4*4];
    float4 cq = *(const float4*)&Whh[(u + 64 )*HID + k4*4];
    float4 dq = *(const float4*)&Whh[(u + 96 )*HID + k4*4];
    wi[2*k4+0] = __builtin_amdgcn_cvt_pkrtz(a.x,  a.y);
    wi[2*k4+1] = __builtin_amdgcn_cvt_pkrtz(a.z,  a.w);
    wf[2*k4+0] = __builtin_amdgcn_cvt_pkrtz(bq.x, bq.y);
    wf[2*k4+1] = __builtin_amdgcn_cvt_pkrtz(bq.z, bq.w);
    wg[2*k4+0] = __builtin_amdgcn_cvt_pkrtz(cq.x, cq.y);
    wg[2*k4+1] = __builtin_amdgcn_cvt_pkrtz(cq.z, cq.w);
    wo[2*k4+0] = __builtin_amdgcn_cvt_pkrtz(dq.x, dq.y);
    wo[2*k4+1] = __builtin_amdgcn_cvt_pkrtz(dq.z, dq.w);
  }

  // head weight row for this lane (head hk, slot hj), packed fp16 pairs
  const int hk = lane >> 4;            // 0..3 (3 = idle group)
  const int hj = lane & 15;            // 0..15 (valid < 9)
  const bool jvalid = (hj < 9) && (hk < 3);
  const int wk = jvalid ? hk : 0;
  const int wj = jvalid ? hj : 0;
  const float* whrow = Wh + (size_t)(wk*NACT + wj)*HID;
  pk16x2 whp[16];
#pragma unroll
  for (int p = 0; p < 8; ++p) {
    float4 v = *(const float4*)&whrow[p*4];
    whp[2*p+0] = __builtin_amdgcn_cvt_pkrtz(v.x, v.y);
    whp[2*p+1] = __builtin_amdgcn_cvt_pkrtz(v.z, v.w);
  }
  const float bhv = jvalid ? bh[wk*NACT + wj] : 0.f;

  // done -> two 64-bit wave-uniform SGPR masks (bit t = done[t,b] != 0)
  unsigned long long dm0 = __ballot(done[lane*Bn + b] != 0);          // t = 0..63
  unsigned long long dm1 = __ballot(done[(lane + 64)*Bn + b] != 0);   // t = 64..127

  float c = c0[row*HID + u];
  float h = h0[row*HID + u];
  unsigned pk = h2bits(__builtin_amdgcn_cvt_pkrtz(h, dpp_swap1(h)));

  const uint2* gbase = G1q + (size_t)row*32 + u;
  const size_t gstride = (size_t)BA*32;          // uint2 per step
  uint2 q0 = gbase[0*gstride];
  uint2 q1 = gbase[1*gstride];
  uint2 q2 = gbase[2*gstride];
  uint2 q3 = gbase[3*gstride];

// head for step TM1 (uses hp[] = h_{TM1} pairs, in scope at expansion site)
#define HEAD_STEP(TM1)                                                     \
  {                                                                        \
    const int tm1 = (TM1);                                                 \
    const int nprev = tm1*BA + row;                                        \
    const int nld = (tm1 < 0) ? row : nprev;                               \
    int av = actions[(size_t)nld*3 + ((lane < 3) ? lane : 0)];             \
    int a0 = __builtin_amdgcn_readlane(av, 0);                             \
    int a1 = __builtin_amdgcn_readlane(av, 1);                             \
    int a2 = __builtin_amdgcn_readlane(av, 2);                             \
    int ak = (hk == 0) ? a0 : ((hk == 1) ? a1 : a2);                       \
    float lg = bhv;                                                        \
    _Pragma("unroll") for (int p = 0; p < 16; ++p)                         \
      lg = dot2(whp[p], bits2h(hp[p]), lg);                                \
    lg = jvalid ? lg : -3.0e38f;                                           \
    float mx = dpp_max16(lg);                                              \
    float e = jvalid ? __expf(lg - mx) : 0.f;                              \
    float s = dpp_sum16(e);                                                \
    float lse = mx + __logf(s);                                            \
    float rs = __builtin_amdgcn_rcpf(s);                                   \
    float lp = lg - lse;                                                   \
    float ent = dpp_sum16(e * rs * lp);                                    \
    float alp = dpp_sum16((jvalid && (hj == ak)) ? lp : 0.f);              \
    float pa = __uint_as_float(__builtin_amdgcn_readlane(__float_as_uint(alp), 0));  \
    float pb = __uint_as_float(__builtin_amdgcn_readlane(__float_as_uint(alp), 16)); \
    float pc = __uint_as_float(__builtin_amdgcn_readlane(__float_as_uint(alp), 32)); \
    if (tm1 >= 0) {                                                        \
      if ((hj == 0) && (hk < 3))                                           \
        out[OUT_ENT + (size_t)nprev*3 + hk] = -ent;                        \
      if (lane == 0) out[OUT_LP + nprev] = pa * pb * pc;                   \
    }                                                                      \
  }

#define LSTM_PHASE(TT, Q)                                                \
  {                                                                      \
    uint2 cur = Q;                                                       \
    int tnx = (TT) + 4; tnx = (tnx < Tn) ? tnx : (Tn - 1);               \
    Q = gbase[(size_t)tnx * gstride];                                    \
    unsigned long long dbit = ((TT) < 64) ? (dm0 >> (TT))                \
                                          : (dm1 >> ((TT) - 64));        \
    float m = (dbit & 1ull) ? 0.f : 1.f;   /* scalar-pipe select */      \
    unsigned hp[16];                                                     \
    _Pragma("unroll") for (int k = 0; k < 16; ++k)                       \
      hp[k] = __builtin_amdgcn_readlane(pk, 2*k);                        \
    float ai0=0.f, ai1=0.f, af0=0.f, af1=0.f;                            \
    float ag0=0.f, ag1=0.f, ao0=0.f, ao1=0.f;                            \
    _Pragma("unroll") for (int k = 0; k < 16; k += 2) {                  \
      pk16x2 ha = bits2h(hp[k]), hb = bits2h(hp[k+1]);                   \
      ai0 = dot2(wi[k], ha, ai0); ai1 = dot2(wi[k+1], hb, ai1);          \
      af0 = dot2(wf[k], ha, af0); af1 = dot2(wf[k+1], hb, af1);          \
      ag0 = dot2(wg[k], ha, ag0); ag1 = dot2(wg[k+1], hb, ag1);          \
      ao0 = dot2(wo[k], ha, ao0); ao1 = dot2(wo[k+1], hb, ao1);          \
    }                                                                    \
    pk16x2 ig = bits2h(cur.x), fo = bits2h(cur.y);                       \
    float gi = fmaf(m, ai0 + ai1, (float)ig.x);                          \
    float gf = fmaf(m, af0 + af1, (float)fo.x);                          \
    float gg = fmaf(m, ag0 + ag1, (float)ig.y);                          \
    float go = fmaf(m, ao0 + ao1, (float)fo.y);                          \
    float iv = fast_sig(gi), fv = fast_sig(gf);                          \
    float gv = fast_tanh(gg), ov = fast_sig(go);                         \
    c = fmaf(fv, m * c, iv * gv);                                        \
    h = ov * fast_tanh(c);                                               \
    pk = h2bits(__builtin_amdgcn_cvt_pkrtz(h, dpp_swap1(h)));            \
    HEAD_STEP((TT) - 1)                                                  \
  }

  for (int t = 0; t < Tn; t += 4) {
    LSTM_PHASE(t + 0, q0)
    LSTM_PHASE(t + 1, q1)
    LSTM_PHASE(t + 2, q2)
    LSTM_PHASE(t + 3, q3)
  }

  // tail: head for the final step (t = 127) from the final pk
  {
    unsigned hp[16];
#pragma unroll
    for (int k = 0; k < 16; ++k)
      hp[k] = __builtin_amdgcn_readlane(pk, 2*k);
    HEAD_STEP(Tn - 1)
  }
#undef LSTM_PHASE
#undef HEAD_STEP
}

extern "C" void kernel_launch(void* const* d_in, const int* in_sizes, int n_in,
                              void* d_out, int out_size, void* d_ws, size_t ws_size,
                              hipStream_t stream)
{
  const float* x       = (const float*)d_in[0];
  const int*   done    = (const int*)  d_in[1];
  const int*   actions = (const int*)  d_in[2];
  const float* W1  = (const float*)d_in[3];
  const float* b1  = (const float*)d_in[4];
  const float* W2  = (const float*)d_in[5];
  const float* b2  = (const float*)d_in[6];
  const float* W3  = (const float*)d_in[7];
  const float* b3  = (const float*)d_in[8];
  const float* Wih = (const float*)d_in[9];
  const float* Whh = (const float*)d_in[10];
  const float* bih = (const float*)d_in[11];
  const float* bhh = (const float*)d_in[12];
  const float* Wh  = (const float*)d_in[13];
  const float* bh  = (const float*)d_in[14];
  const float* h0  = (const float*)d_in[15];
  const float* c0  = (const float*)d_in[16];
  float* out = (float*)d_out;

  uint2* G1q = (uint2*)d_ws;                         // TBA*32 uint2 = 16.8 MB
  _Float16* W16 = (_Float16*)(G1q + (size_t)TBA*32); // 128 KB

  cvtw_act_kernel<<<W16_TOT/256 + (TBA*Kh)/256, 256, 0, stream>>>(
      W1, W2, W3, Wih, W16, actions, out);
  mlp_kernel<<<TBA/64, 256, 0, stream>>>(x, W16, b1, b2, b3, bih, bhh, G1q);
  lstm_head_kernel<<<BA, 64, 0, stream>>>(G1q, Whh, done, h0, c0,
                                          actions, Wh, bh, out);
}

// Round 11
// 194.287 us; speedup vs baseline: 1.1434x; 1.1434x over previous
//
#include <hip/hip_runtime.h>
#include <math.h>

namespace {
constexpr int Tn = 128, Bn = 16, An = 32, OBS = 256, Kh = 3, NACT = 9, HID = 32;
constexpr int TBA = Tn * Bn * An;   // 65536 rows through the MLP
constexpr int BA  = Bn * An;        // 512 LSTM sequences
constexpr int OUT_LP  = TBA * Kh;         // 196608: logprobs start
constexpr int OUT_ENT = TBA * Kh + TBA;   // 262144: entropies start

// fp16 weight pack offsets (elements)
constexpr int W1_OFF  = 0;       // 128x256
constexpr int W2_OFF  = 32768;   // 128x128
constexpr int W3_OFF  = 49152;   // 64x128
constexpr int WIH_OFF = 57344;   // 128x64
constexpr int W16_TOT = 65536;

typedef __fp16   pk16x2 __attribute__((ext_vector_type(2)));  // builtin-compatible
typedef _Float16 half8v __attribute__((ext_vector_type(8)));
typedef float    f32x4  __attribute__((ext_vector_type(4)));
}

__device__ __forceinline__ float fast_sig(float x) {
  return __builtin_amdgcn_rcpf(1.f + __expf(-x));
}
__device__ __forceinline__ float fast_tanh(float x) {   // 2*sig(2x)-1, saturates safely
  return fmaf(2.f, fast_sig(2.f * x), -1.f);
}
__device__ __forceinline__ unsigned h2bits(pk16x2 h) {
  return __builtin_bit_cast(unsigned, h);
}
__device__ __forceinline__ pk16x2 bits2h(unsigned u) {
  return __builtin_bit_cast(pk16x2, u);
}
__device__ __forceinline__ float dot2(pk16x2 a, pk16x2 b, float c) {
#if __has_builtin(__builtin_amdgcn_fdot2)
  return __builtin_amdgcn_fdot2(a, b, c, false);
#else
  c = fmaf((float)a.x, (float)b.x, c);
  return fmaf((float)a.y, (float)b.y, c);
#endif
}
// swap adjacent lanes (xor 1) via DPP quad_perm(1,0,3,2): VALU, no DS pipe
__device__ __forceinline__ float dpp_swap1(float x) {
  return __uint_as_float((unsigned)__builtin_amdgcn_mov_dpp(
      (int)__float_as_uint(x), 0xB1, 0xF, 0xF, true));
}

// ---------------------------------------------------------------------------
// Weight fp32->fp16 pre-conversion + actions echo (fused, one launch).
// ---------------------------------------------------------------------------
__global__ __launch_bounds__(256) void cvtw_act_kernel(
    const float* __restrict__ W1, const float* __restrict__ W2,
    const float* __restrict__ W3, const float* __restrict__ Wih,
    _Float16* __restrict__ w16, const int* __restrict__ actions,
    float* __restrict__ out)
{
  const int bid = blockIdx.x;
  if (bid < W16_TOT/256) {
    int i = bid * 256 + threadIdx.x;            // 0..65535
    float v;
    if (i < W2_OFF)       v = W1[i];
    else if (i < W3_OFF)  v = W2[i - W2_OFF];
    else if (i < WIH_OFF) v = W3[i - W3_OFF];
    else                  v = Wih[i - WIH_OFF];
    w16[i] = (_Float16)v;
  } else {
    int i = (bid - W16_TOT/256) * 256 + threadIdx.x;  // 0..196607
    out[i] = (float)actions[i];
  }
}

// ---------------------------------------------------------------------------
// Fused MLP trunk + LSTM input projection, f16 MFMA (fp32 accumulate).
// v3: 512 threads (8 waves), 128 rows/block, 512 blocks -> halves per-row
// weight-staging traffic and barrier count. LDS 71.7 KB -> 2 blocks/CU.
// ---------------------------------------------------------------------------
template<int ROWS, int WSTR>
__device__ __forceinline__ void stage_wh(const _Float16* __restrict__ Wg, int kofs,
                                         _Float16* __restrict__ wt, int tid)
{
#pragma unroll
  for (int it = 0; it < ROWS/64; ++it) {        // ROWS*8 units / 512 threads
    int idx = tid + it*512;
    int o = idx >> 3, g8 = idx & 7;
    *(half8v*)&wt[o*72 + g8*8] =
        *(const half8v*)&Wg[(size_t)o*WSTR + kofs + g8*8];
  }
}

template<int NOC, int XSTR>
__device__ __forceinline__ void mfma_slab(const _Float16* __restrict__ xsrc,
                                          const _Float16* __restrict__ wt,
                                          int rA, int ln, int quad, f32x4 acc[8])
{
#pragma unroll
  for (int kc = 0; kc < 2; ++kc) {
    half8v a = *(const half8v*)&xsrc[rA*XSTR + kc*32 + quad*8];
#pragma unroll
    for (int oc = 0; oc < NOC; ++oc) {
      half8v b = *(const half8v*)&wt[(oc*16 + ln)*72 + kc*32 + quad*8];
      acc[oc] = __builtin_amdgcn_mfma_f32_16x16x32_f16(a, b, acc[oc], 0, 0, 0);
    }
  }
}

__global__ __launch_bounds__(512) void mlp_kernel(
    const float* __restrict__ x, const _Float16* __restrict__ w16,
    const float* __restrict__ b1, const float* __restrict__ b2,
    const float* __restrict__ b3, const float* __restrict__ bih,
    const float* __restrict__ bhh, uint2* __restrict__ G1q)
{
  __shared__ __align__(16) _Float16 xs[128*72];    // x k-slab; reused for z
  __shared__ __align__(16) _Float16 wt[128*72];    // weight k-slab
  __shared__ __align__(16) _Float16 act[128*136];  // activations (in place)
  const _Float16* W1h  = w16 + W1_OFF;
  const _Float16* W2h  = w16 + W2_OFF;
  const _Float16* W3h  = w16 + W3_OFF;
  const _Float16* Wihh = w16 + WIH_OFF;
  const int tid  = threadIdx.x;                // 0..511
  const int w    = tid >> 6;                   // 0..7
  const int lane = tid & 63;
  const int ln   = lane & 15;
  const int quad = lane >> 4;
  const int rA   = 16*w + ln;                  // 0..127
  const int r0   = 16*w + quad*4;
  const int R0   = blockIdx.x * 128;
  f32x4 acc[8];

  // ---- layer 1: 256 -> 128, tanh (4 k-slabs of 64) ----
#pragma unroll
  for (int oc = 0; oc < 8; ++oc) acc[oc] = (f32x4)0.f;
  for (int kt = 0; kt < 4; ++kt) {
#pragma unroll
    for (int it = 0; it < 2; ++it) {           // stage x slab [128][64] -> fp16
      int idx = tid + it*512;
      int r = idx >> 3, g8 = idx & 7;
      const float* xp = &x[(size_t)(R0 + r)*OBS + kt*64 + g8*8];
      float4 v0 = *(const float4*)xp;
      float4 v1 = *(const float4*)(xp + 4);
      half8v hv = { (_Float16)v0.x, (_Float16)v0.y, (_Float16)v0.z, (_Float16)v0.w,
                    (_Float16)v1.x, (_Float16)v1.y, (_Float16)v1.z, (_Float16)v1.w };
      *(half8v*)&xs[r*72 + g8*8] = hv;
    }
    stage_wh<128, 256>(W1h, kt*64, wt, tid);
    __syncthreads();
    mfma_slab<8, 72>(xs, wt, rA, ln, quad, acc);
    __syncthreads();
  }
#pragma unroll
  for (int oc = 0; oc < 8; ++oc) {
    int o = oc*16 + ln;
    float bv = b1[o];
#pragma unroll
    for (int r = 0; r < 4; ++r)
      act[(r0 + r)*136 + o] = (_Float16)fast_tanh(acc[oc][r] + bv);
  }

  // ---- layer 2: 128 -> 128, tanh ----
#pragma unroll
  for (int oc = 0; oc < 8; ++oc) acc[oc] = (f32x4)0.f;
  for (int kt = 0; kt < 2; ++kt) {
    stage_wh<128, 128>(W2h, kt*64, wt, tid);
    __syncthreads();                            // publishes act writes + wt
    mfma_slab<8, 136>(act + kt*64, wt, rA, ln, quad, acc);
    __syncthreads();
  }
#pragma unroll
  for (int oc = 0; oc < 8; ++oc) {
    int o = oc*16 + ln;
    float bv = b2[o];
#pragma unroll
    for (int r = 0; r < 4; ++r)
      act[(r0 + r)*136 + o] = (_Float16)fast_tanh(acc[oc][r] + bv);
  }

  // ---- layer 3: 128 -> 64, linear -> z into xs buffer ----
#pragma unroll
  for (int oc = 0; oc < 4; ++oc) acc[oc] = (f32x4)0.f;
  for (int kt = 0; kt < 2; ++kt) {
    stage_wh<64, 128>(W3h, kt*64, wt, tid);
    __syncthreads();
    mfma_slab<4, 136>(act + kt*64, wt, rA, ln, quad, acc);
    __syncthreads();
  }
#pragma unroll
  for (int oc = 0; oc < 4; ++oc) {
    int o = oc*16 + ln;
    float bv = b3[o];
#pragma unroll
    for (int r = 0; r < 4; ++r)
      xs[(r0 + r)*72 + o] = (_Float16)(acc[oc][r] + bv);
  }

  // ---- layer 4: z(64) -> 128 gate inputs, all 4 gates of unit u packed ----
#pragma unroll
  for (int oc = 0; oc < 8; ++oc) acc[oc] = (f32x4)0.f;
  stage_wh<128, 64>(Wihh, 0, wt, tid);
  __syncthreads();                              // publishes z writes + wt
  mfma_slab<8, 72>(xs, wt, rA, ln, quad, acc);
#pragma unroll
  for (int p = 0; p < 2; ++p) {
    int ui = p*16 + ln;
    float bi = bih[ui]      + bhh[ui];
    float bf = bih[ui + 32] + bhh[ui + 32];
    float bg = bih[ui + 64] + bhh[ui + 64];
    float bo = bih[ui + 96] + bhh[ui + 96];
#pragma unroll
    for (int r = 0; r < 4; ++r) {
      int n = R0 + r0 + r;
      uint2 q;
      q.x = h2bits(__builtin_amdgcn_cvt_pkrtz(acc[p  ][r] + bi, acc[p+4][r] + bg));
      q.y = h2bits(__builtin_amdgcn_cvt_pkrtz(acc[p+2][r] + bf, acc[p+6][r] + bo));
      G1q[(size_t)n*32 + ui] = q;
    }
  }
}

// ---------------------------------------------------------------------------
// LSTM scan v9: 1 row per 64-lane wave, 512 blocks, zero DS-pipe recurrence
// (SGPR done-masks, DPP h-swap). G1 loads: 8-phase software pipeline with
// distinct registers -> 8 outstanding loads (vmcnt(7) slack). If per-step
// time was latency-bound at depth 4 (step ~ L/4), depth 8 halves it.
// ---------------------------------------------------------------------------
__global__ __launch_bounds__(64) void lstm_kernel(
    const uint2* __restrict__ G1q, const float* __restrict__ Whh,
    const int* __restrict__ done, const float* __restrict__ h0,
    const float* __restrict__ c0, unsigned* __restrict__ Y16)
{
  const int lane = threadIdx.x;        // 0..63
  const int u = lane & 31;
  const int row = blockIdx.x;          // 0..511
  const int b = row >> 5;

  pk16x2 wi[16], wf[16], wg[16], wo[16];   // Whh rows u, u+32, u+64, u+96
#pragma unroll
  for (int k4 = 0; k4 < 8; ++k4) {
    float4 a  = *(const float4*)&Whh[(u      )*HID + k4*4];
    float4 bq = *(const float4*)&Whh[(u + 32 )*HID + k4*4];
    float4 cq = *(const float4*)&Whh[(u + 64 )*HID + k4*4];
    float4 dq = *(const float4*)&Whh[(u + 96 )*HID + k4*4];
    wi[2*k4+0] = __builtin_amdgcn_cvt_pkrtz(a.x,  a.y);
    wi[2*k4+1] = __builtin_amdgcn_cvt_pkrtz(a.z,  a.w);
    wf[2*k4+0] = __builtin_amdgcn_cvt_pkrtz(bq.x, bq.y);
    wf[2*k4+1] = __builtin_amdgcn_cvt_pkrtz(bq.z, bq.w);
    wg[2*k4+0] = __builtin_amdgcn_cvt_pkrtz(cq.x, cq.y);
    wg[2*k4+1] = __builtin_amdgcn_cvt_pkrtz(cq.z, cq.w);
    wo[2*k4+0] = __builtin_amdgcn_cvt_pkrtz(dq.x, dq.y);
    wo[2*k4+1] = __builtin_amdgcn_cvt_pkrtz(dq.z, dq.w);
  }

  // done -> two 64-bit wave-uniform SGPR masks (bit t = done[t,b] != 0)
  unsigned long long dm0 = __ballot(done[lane*Bn + b] != 0);          // t = 0..63
  unsigned long long dm1 = __ballot(done[(lane + 64)*Bn + b] != 0);   // t = 64..127

  float c = c0[row*HID + u];
  float h = h0[row*HID + u];
  unsigned pk = h2bits(__builtin_amdgcn_cvt_pkrtz(h, dpp_swap1(h)));

  const uint2* gbase = G1q + (size_t)row*32 + u;
  const size_t gstride = (size_t)BA*32;          // uint2 per step
  uint2 q0 = gbase[0*gstride];
  uint2 q1 = gbase[1*gstride];
  uint2 q2 = gbase[2*gstride];
  uint2 q3 = gbase[3*gstride];
  uint2 q4 = gbase[4*gstride];
  uint2 q5 = gbase[5*gstride];
  uint2 q6 = gbase[6*gstride];
  uint2 q7 = gbase[7*gstride];

#define LSTM_PHASE(TT, Q)                                                \
  {                                                                      \
    uint2 cur = Q;                                                       \
    int tnx = (TT) + 8; tnx = (tnx < Tn) ? tnx : (Tn - 1);               \
    Q = gbase[(size_t)tnx * gstride];                                    \
    unsigned long long dbit = ((TT) < 64) ? (dm0 >> (TT))                \
                                          : (dm1 >> ((TT) - 64));        \
    float m = (dbit & 1ull) ? 0.f : 1.f;   /* scalar-pipe select */      \
    unsigned hp[16];                                                     \
    _Pragma("unroll") for (int k = 0; k < 16; ++k)                       \
      hp[k] = __builtin_amdgcn_readlane(pk, 2*k);                        \
    float ai0=0.f, ai1=0.f, af0=0.f, af1=0.f;                            \
    float ag0=0.f, ag1=0.f, ao0=0.f, ao1=0.f;                            \
    _Pragma("unroll") for (int k = 0; k < 16; k += 2) {                  \
      pk16x2 ha = bits2h(hp[k]), hb = bits2h(hp[k+1]);                   \
      ai0 = dot2(wi[k], ha, ai0); ai1 = dot2(wi[k+1], hb, ai1);          \
      af0 = dot2(wf[k], ha, af0); af1 = dot2(wf[k+1], hb, af1);          \
      ag0 = dot2(wg[k], ha, ag0); ag1 = dot2(wg[k+1], hb, ag1);          \
      ao0 = dot2(wo[k], ha, ao0); ao1 = dot2(wo[k+1], hb, ao1);          \
    }                                                                    \
    pk16x2 ig = bits2h(cur.x), fo = bits2h(cur.y);                       \
    float gi = fmaf(m, ai0 + ai1, (float)ig.x);                          \
    float gf = fmaf(m, af0 + af1, (float)fo.x);                          \
    float gg = fmaf(m, ag0 + ag1, (float)ig.y);                          \
    float go = fmaf(m, ao0 + ao1, (float)fo.y);                          \
    float iv = fast_sig(gi), fv = fast_sig(gf);                          \
    float gv = fast_tanh(gg), ov = fast_sig(go);                         \
    c = fmaf(fv, m * c, iv * gv);                                        \
    h = ov * fast_tanh(c);                                               \
    pk = h2bits(__builtin_amdgcn_cvt_pkrtz(h, dpp_swap1(h)));            \
    if ((lane & 33) == 0)                                                \
      Y16[((size_t)(TT)*BA + row)*16 + (u >> 1)] = pk;                   \
  }

  for (int t = 0; t < Tn; t += 8) {
    LSTM_PHASE(t + 0, q0)
    LSTM_PHASE(t + 1, q1)
    LSTM_PHASE(t + 2, q2)
    LSTM_PHASE(t + 3, q3)
    LSTM_PHASE(t + 4, q4)
    LSTM_PHASE(t + 5, q5)
    LSTM_PHASE(t + 6, q6)
    LSTM_PHASE(t + 7, q7)
  }
#undef LSTM_PHASE
}

// ---------------------------------------------------------------------------
// Heads: per row, 27 logits (3 heads x 9), log-softmax, entropy, gather,
// product of chosen log-probs. One thread per row; Y (fp16 pairs) read
// directly from global.
// ---------------------------------------------------------------------------
__global__ __launch_bounds__(256) void head_kernel(
    const unsigned* __restrict__ Y16, const float* __restrict__ Wh,
    const float* __restrict__ bh, const int* __restrict__ actions,
    float* __restrict__ out)
{
  __shared__ __align__(16) float whs[27*32];
  __shared__ float bhs[32];
  const int tid = threadIdx.x;
  const int R0 = blockIdx.x * 256;
  for (int i = tid; i < 27*32; i += 256) whs[i] = Wh[i];
  if (tid < 27) bhs[tid] = bh[tid];
  const int row = R0 + tid;
  float yv[32];
#pragma unroll
  for (int i4 = 0; i4 < 4; ++i4) {
    uint4 yw = *(const uint4*)&Y16[(size_t)row*16 + i4*4];
    pk16x2 p0 = bits2h(yw.x), p1 = bits2h(yw.y), p2 = bits2h(yw.z), p3 = bits2h(yw.w);
    yv[i4*8+0] = (float)p0.x; yv[i4*8+1] = (float)p0.y;
    yv[i4*8+2] = (float)p1.x; yv[i4*8+3] = (float)p1.y;
    yv[i4*8+4] = (float)p2.x; yv[i4*8+5] = (float)p2.y;
    yv[i4*8+6] = (float)p3.x; yv[i4*8+7] = (float)p3.y;
  }
  __syncthreads();
  float l[27];
#pragma unroll
  for (int m = 0; m < 27; ++m) {
    float a = bhs[m];
#pragma unroll
    for (int k4 = 0; k4 < 8; ++k4) {
      float4 w4 = *(const float4*)&whs[m*32 + k4*4];   // uniform -> broadcast
      a = fmaf(yv[k4*4+0], w4.x, a);
      a = fmaf(yv[k4*4+1], w4.y, a);
      a = fmaf(yv[k4*4+2], w4.z, a);
      a = fmaf(yv[k4*4+3], w4.w, a);
    }
    l[m] = a;
  }
  float logprob = 1.0f;
#pragma unroll
  for (int kk = 0; kk < 3; ++kk) {
    float mx = l[kk*9];
#pragma unroll
    for (int n = 1; n < 9; ++n) mx = fmaxf(mx, l[kk*9+n]);
    float s = 0.f;
#pragma unroll
    for (int n = 0; n < 9; ++n) s += __expf(l[kk*9+n] - mx);
    float lse = mx + __logf(s);
    float ent = 0.f;
#pragma unroll
    for (int n = 0; n < 9; ++n) {
      float lp = l[kk*9+n] - lse;
      ent -= __expf(lp) * lp;
    }
    int a = actions[row*3 + kk];
    float alp = 0.f;
#pragma unroll
    for (int n = 0; n < 9; ++n) alp = (a == n) ? (l[kk*9+n] - lse) : alp;
    logprob *= alp;
    out[OUT_ENT + row*3 + kk] = ent;     // actions echoed by cvtw_act_kernel
  }
  out[OUT_LP + row] = logprob;
}

extern "C" void kernel_launch(void* const* d_in, const int* in_sizes, int n_in,
                              void* d_out, int out_size, void* d_ws, size_t ws_size,
                              hipStream_t stream)
{
  const float* x       = (const float*)d_in[0];
  const int*   done    = (const int*)  d_in[1];
  const int*   actions = (const int*)  d_in[2];
  const float* W1  = (const float*)d_in[3];
  const float* b1  = (const float*)d_in[4];
  const float* W2  = (const float*)d_in[5];
  const float* b2  = (const float*)d_in[6];
  const float* W3  = (const float*)d_in[7];
  const float* b3  = (const float*)d_in[8];
  const float* Wih = (const float*)d_in[9];
  const float* Whh = (const float*)d_in[10];
  const float* bih = (const float*)d_in[11];
  const float* bhh = (const float*)d_in[12];
  const float* Wh  = (const float*)d_in[13];
  const float* bh  = (const float*)d_in[14];
  const float* h0  = (const float*)d_in[15];
  const float* c0  = (const float*)d_in[16];
  float* out = (float*)d_out;

  uint2* G1q = (uint2*)d_ws;                         // TBA*32 uint2 = 16.8 MB
  unsigned* Y16 = (unsigned*)(G1q + (size_t)TBA*32); // TBA*16 uints =  4.2 MB
  _Float16* W16 = (_Float16*)(Y16 + (size_t)TBA*16); // 128 KB

  cvtw_act_kernel<<<W16_TOT/256 + (TBA*Kh)/256, 256, 0, stream>>>(
      W1, W2, W3, Wih, W16, actions, out);
  mlp_kernel<<<TBA/128, 512, 0, stream>>>(x, W16, b1, b2, b3, bih, bhh, G1q);
  lstm_kernel<<<BA, 64, 0, stream>>>(G1q, Whh, done, h0, c0, Y16);
  head_kernel<<<TBA/256, 256, 0, stream>>>(Y16, Wh, bh, actions, out);
}